// Round 8
// baseline (191.560 us; speedup 1.0000x reference)
//
#include <hip/hip_runtime.h>
#include <hip/hip_bf16.h>
#include <math.h>

typedef float f32x4 __attribute__((ext_vector_type(4)));
typedef int   i32x4 __attribute__((ext_vector_type(4)));
typedef int   i32x8 __attribute__((ext_vector_type(8)));

#define BSZ 8192
#define DIM 2048
#define NTILE 64           // 8192 / 128 tiles per side
#define ROWB (DIM / 2)     // fp4 row stride in bytes = 1024
#define BKB 128            // K-step slice per row in BYTES = 256 fp4 elements
#define KSTEPS 8           // 2048 / 256

// MX e8m0 scale byte for 2^-6 (inputs pre-scaled by 64): 127-6 = 121 = 0x79
#define SCALE_I32 0x79797979

// ---------- e2m1 fp4 encode (round to nearest) ----------
// values: 0:0 1:.5 2:1 3:1.5 4:2 5:3 6:4 7:6 ; bit3 = sign
__device__ __forceinline__ unsigned f2fp4(float v) {
  float a = fabsf(v);
  unsigned s = (__float_as_uint(v) >> 31) << 3;
  unsigned m = (a < 0.25f) ? 0u
             : (a < 0.75f) ? 1u
             : (a < 1.25f) ? 2u
             : (a < 1.75f) ? 3u
             : (a < 2.5f)  ? 4u
             : (a < 3.5f)  ? 5u
             : (a < 5.0f)  ? 6u : 7u;
  return s | m;
}

// ---------- kernel 1: fused normalize -> fp4(x*64), diag cos (fp32) ----------
__global__ void __launch_bounds__(256) k_prep(const float* __restrict__ X,
                                              const float* __restrict__ Y,
                                              unsigned char* __restrict__ Xq,
                                              unsigned char* __restrict__ Yq,
                                              float* __restrict__ dg) {
  const int row = blockIdx.x;
  const int tid = threadIdx.x;
  const float4* xp = (const float4*)(X + (size_t)row * DIM);
  const float4* yp = (const float4*)(Y + (size_t)row * DIM);
  float4 x0 = xp[tid * 2], x1 = xp[tid * 2 + 1];
  float4 y0 = yp[tid * 2], y1 = yp[tid * 2 + 1];
  float sxx = x0.x*x0.x + x0.y*x0.y + x0.z*x0.z + x0.w*x0.w
            + x1.x*x1.x + x1.y*x1.y + x1.z*x1.z + x1.w*x1.w;
  float syy = y0.x*y0.x + y0.y*y0.y + y0.z*y0.z + y0.w*y0.w
            + y1.x*y1.x + y1.y*y1.y + y1.z*y1.z + y1.w*y1.w;
  float sxy = x0.x*y0.x + x0.y*y0.y + x0.z*y0.z + x0.w*y0.w
            + x1.x*y1.x + x1.y*y1.y + x1.z*y1.z + x1.w*y1.w;
#pragma unroll
  for (int m = 32; m >= 1; m >>= 1) {
    sxx += __shfl_xor(sxx, m);
    syy += __shfl_xor(syy, m);
    sxy += __shfl_xor(sxy, m);
  }
  __shared__ float sh[3][4];
  if ((tid & 63) == 0) {
    sh[0][tid >> 6] = sxx; sh[1][tid >> 6] = syy; sh[2][tid >> 6] = sxy;
  }
  __syncthreads();
  float xx = sh[0][0] + sh[0][1] + sh[0][2] + sh[0][3];
  float yy = sh[1][0] + sh[1][1] + sh[1][2] + sh[1][3];
  float xy = sh[2][0] + sh[2][1] + sh[2][2] + sh[2][3];
  float nx = fmaxf(sqrtf(xx), 1e-8f);
  float ny = fmaxf(sqrtf(yy), 1e-8f);
  float ix = 64.0f / nx, iy = 64.0f / ny;   // x64 pre-scale onto e2m1 grid
  float vx[8] = {x0.x, x0.y, x0.z, x0.w, x1.x, x1.y, x1.z, x1.w};
  float vy[8] = {y0.x, y0.y, y0.z, y0.w, y1.x, y1.y, y1.z, y1.w};
  unsigned ux = 0, uy = 0;
#pragma unroll
  for (int i = 0; i < 8; ++i) {
    ux |= f2fp4(vx[i] * ix) << (4 * i);
    uy |= f2fp4(vy[i] * iy) << (4 * i);
  }
  *(unsigned*)(Xq + (size_t)row * ROWB + tid * 4) = ux;
  *(unsigned*)(Yq + (size_t)row * ROWB + tid * 4) = uy;
  if (tid == 0) dg[row] = xy / (nx * ny);
}

// ---------- kernel 2: 128x128-tile MX-fp4 GEMM, single-barrier double-buffer ----------
// Round-7 verified fp4 kernel with ONE structural change: double-buffered LDS,
// STAGE(t+1) issued BEFORE compute of tile t, single __syncthreads per K-step
// (vmcnt(0)+lgkmcnt(0)+s_barrier). Natural block raster (no XCD swizzle) to
// deconfound round 5's FETCH explosion.
// Hazards: RAW - reads of buf[t&1] need STAGE(t) (issued at t-1) complete:
// guaranteed by the vmcnt(0) inside the end-of-(t-1) __syncthreads. WAR -
// STAGE(t+1) overwrites buf[(t+1)&1], last read at iter t-1; those ds_reads
// completed before the end-of-(t-1) barrier, and the stage is issued after it.
// LDS XOR-8 swizzle unchanged (rule #21): physical 16B chunk p of row r holds
// logical chunk p ^ (r&7); inverse on global source, forward on ds_read.
__global__ void __launch_bounds__(256) k_gemm(const unsigned char* __restrict__ Xq,
                                              const unsigned char* __restrict__ Yq,
                                              float* __restrict__ rowpart,
                                              float* __restrict__ colpart) {
  const int bm = blockIdx.x & (NTILE - 1);
  const int bn = blockIdx.x >> 6;
  const int tileRow = bm * 128;
  const int tileCol = bn * 128;

  __shared__ __align__(16) unsigned char As[2][128][BKB];   // 2 x 16 KiB
  __shared__ __align__(16) unsigned char Bs[2][128][BKB];   // 2 x 16 KiB
  __shared__ float rsum2[2][128];
  __shared__ float csum2[2][128];

  const int tid = threadIdx.x;
  const int lane = tid & 63;
  const int w = tid >> 6;        // wave 0..3
  const int wr = w >> 1;         // wave row 0..1  (64-row sub-tile)
  const int wc = w & 1;          // wave col 0..1  (64-col sub-tile)
  const int lo = lane & 15;
  const int hi = lane >> 4;      // k-quarter within one mfma (32 elems = 16 B)

  f32x4 acc[4][4];
#pragma unroll
  for (int m = 0; m < 4; ++m)
#pragma unroll
    for (int n = 0; n < 4; ++n) acc[m][n] = (f32x4){0.f, 0.f, 0.f, 0.f};

  // staging: wave w covers rows [w*32, w*32+32), 8 rows x 128 B per issue.
  // lane l: row +(l>>3), physical chunk l&7 <- logical chunk (l&7)^(l>>3).
  const size_t lrow = (size_t)(lane >> 3);
  const int    lcol = (((lane & 7) ^ (lane >> 3)) * 16);
  const unsigned char* gxa = Xq + ((size_t)(tileRow + w * 32) + lrow) * ROWB + lcol;
  const unsigned char* gyb = Yq + ((size_t)(tileCol + w * 32) + lrow) * ROWB + lcol;

#define STAGE(tt, bi) do {                                                             \
    const int kb_ = (tt) * BKB;                                                        \
    _Pragma("unroll")                                                                  \
    for (int i_ = 0; i_ < 4; ++i_) {                                                   \
      __builtin_amdgcn_global_load_lds(                                                \
          (const __attribute__((address_space(1))) void*)(gxa + (size_t)i_ * 8 * ROWB + kb_), \
          (__attribute__((address_space(3))) void*)&As[bi][w * 32 + i_ * 8][0],        \
          16, 0, 0);                                                                   \
      __builtin_amdgcn_global_load_lds(                                                \
          (const __attribute__((address_space(1))) void*)(gyb + (size_t)i_ * 8 * ROWB + kb_), \
          (__attribute__((address_space(3))) void*)&Bs[bi][w * 32 + i_ * 8][0],        \
          16, 0, 0);                                                                   \
    }                                                                                  \
  } while (0)

  // prologue: tile 0 into buf 0
  STAGE(0, 0);
  __syncthreads();

  for (int t = 0; t < KSTEPS; ++t) {
    if (t + 1 < KSTEPS) STAGE(t + 1, (t + 1) & 1);

    // two mfma K-halves per step: kk=0 -> logical chunks 0..3, kk=1 -> 4..7.
    // lane's 16 B = k elems (kk*128 + hi*32 .. +31); physical chunk =
    // (kk*4 + hi) ^ (lo&7).
#pragma unroll
    for (int kk = 0; kk < 2; ++kk) {
      i32x4 a[4], b[4];
#pragma unroll
      for (int m = 0; m < 4; ++m)
        a[m] = *(const i32x4*)&As[t & 1][wr * 64 + m * 16 + lo][((kk * 4 + hi) ^ (lo & 7)) * 16];
#pragma unroll
      for (int n = 0; n < 4; ++n)
        b[n] = *(const i32x4*)&Bs[t & 1][wc * 64 + n * 16 + lo][((kk * 4 + hi) ^ (lo & 7)) * 16];
#pragma unroll
      for (int m = 0; m < 4; ++m) {
        i32x8 av = {a[m][0], a[m][1], a[m][2], a[m][3], 0, 0, 0, 0};
#pragma unroll
        for (int n = 0; n < 4; ++n) {
          i32x8 bv = {b[n][0], b[n][1], b[n][2], b[n][3], 0, 0, 0, 0};
          acc[m][n] = __builtin_amdgcn_mfma_scale_f32_16x16x128_f8f6f4(
              av, bv, acc[m][n],
              4, 4,                 // cbsz/blgp = FP4 (e2m1)
              0, SCALE_I32,         // scale_a (2^-6)
              0, SCALE_I32);        // scale_b (2^-6)
        }
      }
    }

    // single barrier per K-step: waits this wave's STAGE(t+1) loads (vmcnt 0)
    // and all waves' ds_reads (lgkmcnt 0), then syncs.
    __syncthreads();
  }
#undef STAGE

  // ---- epilogue: exp + per-tile row/col sums ----
  // D layout (16x16 shapes): row = m*16 + hi*4 + q, col = n*16 + lo
  float rp[4][4];
  float cp[4];
#pragma unroll
  for (int m = 0; m < 4; ++m)
#pragma unroll
    for (int q = 0; q < 4; ++q) rp[m][q] = 0.f;
#pragma unroll
  for (int n = 0; n < 4; ++n) cp[n] = 0.f;

#pragma unroll
  for (int m = 0; m < 4; ++m)
#pragma unroll
    for (int n = 0; n < 4; ++n)
#pragma unroll
      for (int q = 0; q < 4; ++q) {
        float e = __expf(acc[m][n][q]);
        rp[m][q] += e;
        cp[n] += e;
      }

#pragma unroll
  for (int m = 0; m < 4; ++m)
#pragma unroll
    for (int q = 0; q < 4; ++q) {
      float v = rp[m][q];
      v += __shfl_xor(v, 1);
      v += __shfl_xor(v, 2);
      v += __shfl_xor(v, 4);
      v += __shfl_xor(v, 8);
      rp[m][q] = v;
    }
#pragma unroll
  for (int n = 0; n < 4; ++n) {
    float v = cp[n];
    v += __shfl_xor(v, 16);
    v += __shfl_xor(v, 32);
    cp[n] = v;
  }

  if (lo == 0) {
#pragma unroll
    for (int m = 0; m < 4; ++m)
#pragma unroll
      for (int q = 0; q < 4; ++q)
        rsum2[wc][wr * 64 + m * 16 + hi * 4 + q] = rp[m][q];
  }
  if (hi == 0) {
#pragma unroll
    for (int n = 0; n < 4; ++n)
      csum2[wr][wc * 64 + n * 16 + lo] = cp[n];
  }
  __syncthreads();

  if (tid < 128) {
    rowpart[(size_t)bn * BSZ + tileRow + tid] = rsum2[0][tid] + rsum2[1][tid];
    colpart[(size_t)bm * BSZ + tileCol + tid] = csum2[0][tid] + csum2[1][tid];
  }
}

// ---------- kernel 3: reduce partials + final expression ----------
__global__ void __launch_bounds__(256) k_final(const float* __restrict__ rowpart,
                                               const float* __restrict__ colpart,
                                               const float* __restrict__ dg,
                                               float* __restrict__ out) {
  const int k = blockIdx.x * 256 + threadIdx.x;
  float rs = 0.f, cs = 0.f;
#pragma unroll 8
  for (int s = 0; s < NTILE; ++s) {
    rs += rowpart[(size_t)s * BSZ + k];
    cs += colpart[(size_t)s * BSZ + k];
  }
  float d = dg[k];
  float p = __expf(d);
  out[k] = logf(cs - p) + logf(rs - p) - 2.0f * d;
}

extern "C" void kernel_launch(void* const* d_in, const int* in_sizes, int n_in,
                              void* d_out, int out_size, void* d_ws, size_t ws_size,
                              hipStream_t stream) {
  const float* X = (const float*)d_in[0];
  const float* Y = (const float*)d_in[1];
  float* out = (float*)d_out;

  char* ws = (char*)d_ws;
  // layout: Xq (8MB) | Yq (8MB) | diag (32KB) | rowpart (2MB) | colpart (2MB)
  unsigned char* Xq = (unsigned char*)ws;
  unsigned char* Yq = (unsigned char*)(ws + (size_t)BSZ * ROWB);
  float* diag = (float*)(ws + (size_t)BSZ * ROWB * 2);
  float* rowpart = (float*)(ws + (size_t)BSZ * ROWB * 2 + BSZ * 4);
  float* colpart = (float*)(ws + (size_t)BSZ * ROWB * 2 + BSZ * 4 + (size_t)NTILE * BSZ * 4);

  k_prep<<<BSZ, 256, 0, stream>>>(X, Y, Xq, Yq, diag);
  k_gemm<<<NTILE * NTILE, 256, 0, stream>>>(Xq, Yq, rowpart, colpart);
  k_final<<<BSZ / 256, 256, 0, stream>>>(rowpart, colpart, diag, out);
}

// Round 9
// 127.688 us; speedup vs baseline: 1.5002x; 1.5002x over previous
//
#include <hip/hip_runtime.h>
#include <hip/hip_bf16.h>
#include <math.h>

typedef float f32x4 __attribute__((ext_vector_type(4)));
typedef int   i32x4 __attribute__((ext_vector_type(4)));
typedef int   i32x8 __attribute__((ext_vector_type(8)));

#define BSZ 8192
#define DIM 2048
#define NTILE 64           // 8192 / 128 tiles per side
#define NKG 16             // k-groups of 128 elements

// MX e8m0 scale byte for 2^-6 (inputs pre-scaled by 64): 127-6 = 121 = 0x79
#define SCALE_I32 0x79797979

// Fragment-major fp4 layout:
//   frag(g, R) = 1024 B, g = k/128 (0..15), R = row/16 (0..511)
//   frag base byte = ((g << 9) + R) << 10
//   within frag: lane (lo = row&15, hi = (k%128)/32) at byte (hi*16+lo)*16,
//   holding row R*16+lo, k elems g*128 + hi*32 .. +31 (2 elems/byte, ascending)
// This is exactly the operand layout mfma_scale_*_f8f6f4 (fp4) consumes, so
// one global_load_dwordx4 per lane = one fragment, fully coalesced (1 KB).

// ---------- e2m1 fp4 encode (round to nearest) ----------
__device__ __forceinline__ unsigned f2fp4(float v) {
  float a = fabsf(v);
  unsigned s = (__float_as_uint(v) >> 31) << 3;
  unsigned m = (a < 0.25f) ? 0u
             : (a < 0.75f) ? 1u
             : (a < 1.25f) ? 2u
             : (a < 1.75f) ? 3u
             : (a < 2.5f)  ? 4u
             : (a < 3.5f)  ? 5u
             : (a < 5.0f)  ? 6u : 7u;
  return s | m;
}

// ---------- kernel 1: fused normalize -> fp4(x*64) in fragment order, diag ----------
__global__ void __launch_bounds__(256) k_prep(const float* __restrict__ X,
                                              const float* __restrict__ Y,
                                              unsigned char* __restrict__ Xq,
                                              unsigned char* __restrict__ Yq,
                                              float* __restrict__ dg) {
  const int row = blockIdx.x;
  const int tid = threadIdx.x;
  const float4* xp = (const float4*)(X + (size_t)row * DIM);
  const float4* yp = (const float4*)(Y + (size_t)row * DIM);
  float4 x0 = xp[tid * 2], x1 = xp[tid * 2 + 1];
  float4 y0 = yp[tid * 2], y1 = yp[tid * 2 + 1];
  float sxx = x0.x*x0.x + x0.y*x0.y + x0.z*x0.z + x0.w*x0.w
            + x1.x*x1.x + x1.y*x1.y + x1.z*x1.z + x1.w*x1.w;
  float syy = y0.x*y0.x + y0.y*y0.y + y0.z*y0.z + y0.w*y0.w
            + y1.x*y1.x + y1.y*y1.y + y1.z*y1.z + y1.w*y1.w;
  float sxy = x0.x*y0.x + x0.y*y0.y + x0.z*y0.z + x0.w*y0.w
            + x1.x*y1.x + x1.y*y1.y + x1.z*y1.z + x1.w*y1.w;
#pragma unroll
  for (int m = 32; m >= 1; m >>= 1) {
    sxx += __shfl_xor(sxx, m);
    syy += __shfl_xor(syy, m);
    sxy += __shfl_xor(sxy, m);
  }
  __shared__ float sh[3][4];
  if ((tid & 63) == 0) {
    sh[0][tid >> 6] = sxx; sh[1][tid >> 6] = syy; sh[2][tid >> 6] = sxy;
  }
  __syncthreads();
  float xx = sh[0][0] + sh[0][1] + sh[0][2] + sh[0][3];
  float yy = sh[1][0] + sh[1][1] + sh[1][2] + sh[1][3];
  float xy = sh[2][0] + sh[2][1] + sh[2][2] + sh[2][3];
  float nx = fmaxf(sqrtf(xx), 1e-8f);
  float ny = fmaxf(sqrtf(yy), 1e-8f);
  float ix = 64.0f / nx, iy = 64.0f / ny;   // x64 pre-scale onto e2m1 grid
  float vx[8] = {x0.x, x0.y, x0.z, x0.w, x1.x, x1.y, x1.z, x1.w};
  float vy[8] = {y0.x, y0.y, y0.z, y0.w, y1.x, y1.y, y1.z, y1.w};
  unsigned ux = 0, uy = 0;
#pragma unroll
  for (int i = 0; i < 8; ++i) {
    ux |= f2fp4(vx[i] * ix) << (4 * i);
    uy |= f2fp4(vy[i] * iy) << (4 * i);
  }
  // thread tid covers elems e = tid*8 .. +7 of this row
  const unsigned kkg = tid >> 4;            // e/128
  const unsigned hi4 = (tid >> 2) & 3;      // (e%128)/32
  const unsigned byt = (tid & 3) * 4;       // (e%32)/2
  const unsigned R = row >> 4, lo16 = row & 15;
  const size_t addr = (((size_t)(kkg << 9) + R) << 10) + (hi4 * 16 + lo16) * 16 + byt;
  *(unsigned*)(Xq + addr) = ux;
  *(unsigned*)(Yq + addr) = uy;
  if (tid == 0) dg[row] = xy / (nx * ny);
}

// ---------- kernel 2: 128x128-tile MX-fp4 GEMM, NO LDS, NO barriers ----------
// Both operands loaded directly global -> VGPR in fragment order (coalesced
// 1 KB per wave-load). Register double-buffer (2 named sets, static indexing).
// Waves fully independent: no __syncthreads in the K loop; the compiler's
// register dependencies produce counted vmcnt waits (8 loads in flight while
// 16 MFMAs of the previous group execute).
__global__ void __launch_bounds__(256) k_gemm(const unsigned char* __restrict__ Xq,
                                              const unsigned char* __restrict__ Yq,
                                              float* __restrict__ rowpart,
                                              float* __restrict__ colpart) {
  const int bm = blockIdx.x & (NTILE - 1);
  const int bn = blockIdx.x >> 6;
  const int tileRow = bm * 128;
  const int tileCol = bn * 128;

  __shared__ float rsum2[2][128];
  __shared__ float csum2[2][128];

  const int tid = threadIdx.x;
  const int lane = tid & 63;
  const int w = tid >> 6;        // wave 0..3
  const int wr = w >> 1;         // wave row 0..1  (64-row sub-tile)
  const int wc = w & 1;          // wave col 0..1  (64-col sub-tile)
  const int lo = lane & 15;
  const int hi = lane >> 4;

  f32x4 acc[4][4];
#pragma unroll
  for (int m = 0; m < 4; ++m)
#pragma unroll
    for (int n = 0; n < 4; ++n) acc[m][n] = (f32x4){0.f, 0.f, 0.f, 0.f};

  // per-wave fragment base: A row-blocks bm*8 + wr*4 + m, B: bn*8 + wc*4 + n
  const unsigned char* Ab = Xq + (((size_t)(bm * 8 + wr * 4)) << 10) + lane * 16;
  const unsigned char* Bb = Yq + (((size_t)(bn * 8 + wc * 4)) << 10) + lane * 16;

#define LOADF(da, db, g) do {                                                  \
    const unsigned char* pa_ = Ab + ((size_t)(g) << 19);                       \
    const unsigned char* pb_ = Bb + ((size_t)(g) << 19);                       \
    da[0] = *(const i32x4*)(pa_);                                              \
    da[1] = *(const i32x4*)(pa_ + 1024);                                       \
    da[2] = *(const i32x4*)(pa_ + 2048);                                       \
    da[3] = *(const i32x4*)(pa_ + 3072);                                       \
    db[0] = *(const i32x4*)(pb_);                                              \
    db[1] = *(const i32x4*)(pb_ + 1024);                                       \
    db[2] = *(const i32x4*)(pb_ + 2048);                                       \
    db[3] = *(const i32x4*)(pb_ + 3072);                                       \
  } while (0)

#define MM(aa, bb) do {                                                        \
    _Pragma("unroll")                                                          \
    for (int m_ = 0; m_ < 4; ++m_) {                                           \
      i32x8 av_ = {aa[m_][0], aa[m_][1], aa[m_][2], aa[m_][3], 0, 0, 0, 0};    \
      _Pragma("unroll")                                                        \
      for (int n_ = 0; n_ < 4; ++n_) {                                         \
        i32x8 bv_ = {bb[n_][0], bb[n_][1], bb[n_][2], bb[n_][3], 0, 0, 0, 0};  \
        acc[m_][n_] = __builtin_amdgcn_mfma_scale_f32_16x16x128_f8f6f4(        \
            av_, bv_, acc[m_][n_], 4, 4, 0, SCALE_I32, 0, SCALE_I32);          \
      }                                                                        \
    }                                                                          \
  } while (0)

  i32x4 a0[4], b0[4], a1[4], b1[4];
  LOADF(a0, b0, 0);
  for (int g = 0; g < NKG; g += 2) {
    LOADF(a1, b1, g + 1);
    MM(a0, b0);
    if (g + 2 < NKG) LOADF(a0, b0, g + 2);
    MM(a1, b1);
  }
#undef LOADF
#undef MM

  // ---- epilogue: exp + per-tile row/col sums ----
  // D layout (16x16 shapes): row = m*16 + hi*4 + q, col = n*16 + lo
  float rp[4][4];
  float cp[4];
#pragma unroll
  for (int m = 0; m < 4; ++m)
#pragma unroll
    for (int q = 0; q < 4; ++q) rp[m][q] = 0.f;
#pragma unroll
  for (int n = 0; n < 4; ++n) cp[n] = 0.f;

#pragma unroll
  for (int m = 0; m < 4; ++m)
#pragma unroll
    for (int n = 0; n < 4; ++n)
#pragma unroll
      for (int q = 0; q < 4; ++q) {
        float e = __expf(acc[m][n][q]);
        rp[m][q] += e;
        cp[n] += e;
      }

#pragma unroll
  for (int m = 0; m < 4; ++m)
#pragma unroll
    for (int q = 0; q < 4; ++q) {
      float v = rp[m][q];
      v += __shfl_xor(v, 1);
      v += __shfl_xor(v, 2);
      v += __shfl_xor(v, 4);
      v += __shfl_xor(v, 8);
      rp[m][q] = v;
    }
#pragma unroll
  for (int n = 0; n < 4; ++n) {
    float v = cp[n];
    v += __shfl_xor(v, 16);
    v += __shfl_xor(v, 32);
    cp[n] = v;
  }

  if (lo == 0) {
#pragma unroll
    for (int m = 0; m < 4; ++m)
#pragma unroll
      for (int q = 0; q < 4; ++q)
        rsum2[wc][wr * 64 + m * 16 + hi * 4 + q] = rp[m][q];
  }
  if (hi == 0) {
#pragma unroll
    for (int n = 0; n < 4; ++n)
      csum2[wr][wc * 64 + n * 16 + lo] = cp[n];
  }
  __syncthreads();

  if (tid < 128) {
    rowpart[(size_t)bn * BSZ + tileRow + tid] = rsum2[0][tid] + rsum2[1][tid];
    colpart[(size_t)bm * BSZ + tileCol + tid] = csum2[0][tid] + csum2[1][tid];
  }
}

// ---------- kernel 3: reduce partials + final expression ----------
__global__ void __launch_bounds__(256) k_final(const float* __restrict__ rowpart,
                                               const float* __restrict__ colpart,
                                               const float* __restrict__ dg,
                                               float* __restrict__ out) {
  const int k = blockIdx.x * 256 + threadIdx.x;
  float rs = 0.f, cs = 0.f;
#pragma unroll 8
  for (int s = 0; s < NTILE; ++s) {
    rs += rowpart[(size_t)s * BSZ + k];
    cs += colpart[(size_t)s * BSZ + k];
  }
  float d = dg[k];
  float p = __expf(d);
  out[k] = logf(cs - p) + logf(rs - p) - 2.0f * d;
}

extern "C" void kernel_launch(void* const* d_in, const int* in_sizes, int n_in,
                              void* d_out, int out_size, void* d_ws, size_t ws_size,
                              hipStream_t stream) {
  const float* X = (const float*)d_in[0];
  const float* Y = (const float*)d_in[1];
  float* out = (float*)d_out;

  char* ws = (char*)d_ws;
  // layout: Xq (8MB) | Yq (8MB) | diag (32KB) | rowpart (2MB) | colpart (2MB)
  unsigned char* Xq = (unsigned char*)ws;
  unsigned char* Yq = (unsigned char*)(ws + (size_t)BSZ * DIM / 2);
  float* diag = (float*)(ws + (size_t)BSZ * DIM);
  float* rowpart = (float*)(ws + (size_t)BSZ * DIM + BSZ * 4);
  float* colpart = (float*)(ws + (size_t)BSZ * DIM + BSZ * 4 + (size_t)NTILE * BSZ * 4);

  k_prep<<<BSZ, 256, 0, stream>>>(X, Y, Xq, Yq, diag);
  k_gemm<<<NTILE * NTILE, 256, 0, stream>>>(Xq, Yq, rowpart, colpart);
  k_final<<<BSZ / 256, 256, 0, stream>>>(rowpart, colpart, diag, out);
}

// Round 10
// 127.444 us; speedup vs baseline: 1.5031x; 1.0019x over previous
//
#include <hip/hip_runtime.h>
#include <hip/hip_bf16.h>
#include <math.h>

typedef float f32x4 __attribute__((ext_vector_type(4)));
typedef int   i32x4 __attribute__((ext_vector_type(4)));
typedef int   i32x8 __attribute__((ext_vector_type(8)));

#define BSZ 8192
#define DIM 2048
#define NTILE 64           // 8192 / 128 tiles per side
#define NKG 16             // k-groups of 128 elements

// MX e8m0 scale byte for 2^-6 (inputs pre-scaled by 64): 127-6 = 121 = 0x79
#define SCALE_I32 0x79797979

// Fragment-major fp4 layout:
//   frag(g, R) = 1024 B, g = k/128 (0..15), R = row/16 (0..511)
//   frag base byte = ((g << 9) + R) << 10
//   within frag: lane (lo = row&15, hi = (k%128)/32) at byte (hi*16+lo)*16,
//   holding row R*16+lo, k elems g*128 + hi*32 .. +31 (2 elems/byte, ascending)
// One global_load_dwordx4 per lane = one fragment, fully coalesced (1 KB).

// ---------- e2m1 fp4 encode (round to nearest) ----------
__device__ __forceinline__ unsigned f2fp4(float v) {
  float a = fabsf(v);
  unsigned s = (__float_as_uint(v) >> 31) << 3;
  unsigned m = (a < 0.25f) ? 0u
             : (a < 0.75f) ? 1u
             : (a < 1.25f) ? 2u
             : (a < 1.75f) ? 3u
             : (a < 2.5f)  ? 4u
             : (a < 3.5f)  ? 5u
             : (a < 5.0f)  ? 6u : 7u;
  return s | m;
}

// ---------- kernel 1: fused normalize -> fp4(x*64) in fragment order, diag ----------
__global__ void __launch_bounds__(256) k_prep(const float* __restrict__ X,
                                              const float* __restrict__ Y,
                                              unsigned char* __restrict__ Xq,
                                              unsigned char* __restrict__ Yq,
                                              float* __restrict__ dg) {
  const int row = blockIdx.x;
  const int tid = threadIdx.x;
  const float4* xp = (const float4*)(X + (size_t)row * DIM);
  const float4* yp = (const float4*)(Y + (size_t)row * DIM);
  float4 x0 = xp[tid * 2], x1 = xp[tid * 2 + 1];
  float4 y0 = yp[tid * 2], y1 = yp[tid * 2 + 1];
  float sxx = x0.x*x0.x + x0.y*x0.y + x0.z*x0.z + x0.w*x0.w
            + x1.x*x1.x + x1.y*x1.y + x1.z*x1.z + x1.w*x1.w;
  float syy = y0.x*y0.x + y0.y*y0.y + y0.z*y0.z + y0.w*y0.w
            + y1.x*y1.x + y1.y*y1.y + y1.z*y1.z + y1.w*y1.w;
  float sxy = x0.x*y0.x + x0.y*y0.y + x0.z*y0.z + x0.w*y0.w
            + x1.x*y1.x + x1.y*y1.y + x1.z*y1.z + x1.w*y1.w;
#pragma unroll
  for (int m = 32; m >= 1; m >>= 1) {
    sxx += __shfl_xor(sxx, m);
    syy += __shfl_xor(syy, m);
    sxy += __shfl_xor(sxy, m);
  }
  __shared__ float sh[3][4];
  if ((tid & 63) == 0) {
    sh[0][tid >> 6] = sxx; sh[1][tid >> 6] = syy; sh[2][tid >> 6] = sxy;
  }
  __syncthreads();
  float xx = sh[0][0] + sh[0][1] + sh[0][2] + sh[0][3];
  float yy = sh[1][0] + sh[1][1] + sh[1][2] + sh[1][3];
  float xy = sh[2][0] + sh[2][1] + sh[2][2] + sh[2][3];
  float nx = fmaxf(sqrtf(xx), 1e-8f);
  float ny = fmaxf(sqrtf(yy), 1e-8f);
  float ix = 64.0f / nx, iy = 64.0f / ny;   // x64 pre-scale onto e2m1 grid
  float vx[8] = {x0.x, x0.y, x0.z, x0.w, x1.x, x1.y, x1.z, x1.w};
  float vy[8] = {y0.x, y0.y, y0.z, y0.w, y1.x, y1.y, y1.z, y1.w};
  unsigned ux = 0, uy = 0;
#pragma unroll
  for (int i = 0; i < 8; ++i) {
    ux |= f2fp4(vx[i] * ix) << (4 * i);
    uy |= f2fp4(vy[i] * iy) << (4 * i);
  }
  // thread tid covers elems e = tid*8 .. +7 of this row
  const unsigned kkg = tid >> 4;            // e/128
  const unsigned hi4 = (tid >> 2) & 3;      // (e%128)/32
  const unsigned byt = (tid & 3) * 4;       // (e%32)/2
  const unsigned R = row >> 4, lo16 = row & 15;
  const size_t addr = (((size_t)(kkg << 9) + R) << 10) + (hi4 * 16 + lo16) * 16 + byt;
  *(unsigned*)(Xq + addr) = ux;
  *(unsigned*)(Yq + addr) = uy;
  if (tid == 0) dg[row] = xy / (nx * ny);
}

// ---------- kernel 2: 128x128-tile MX-fp4 GEMM, NO LDS, NO barriers ----------
// Round-9 structure with ONE change: depth-3 register pipeline (loads issued
// 2 k-groups ahead, 16 loads in flight). Full unroll keeps %3 indices static
// (rule #20). Unified reg budget ~104 VGPR + 64 AGPR = 168 -> still
// 3 waves/SIMD (depth-4 would tip to 2: avoided).
__global__ void __launch_bounds__(256) k_gemm(const unsigned char* __restrict__ Xq,
                                              const unsigned char* __restrict__ Yq,
                                              float* __restrict__ rowpart,
                                              float* __restrict__ colpart) {
  const int bm = blockIdx.x & (NTILE - 1);
  const int bn = blockIdx.x >> 6;
  const int tileRow = bm * 128;
  const int tileCol = bn * 128;

  __shared__ float rsum2[2][128];
  __shared__ float csum2[2][128];

  const int tid = threadIdx.x;
  const int lane = tid & 63;
  const int w = tid >> 6;        // wave 0..3
  const int wr = w >> 1;         // wave row 0..1  (64-row sub-tile)
  const int wc = w & 1;          // wave col 0..1  (64-col sub-tile)
  const int lo = lane & 15;
  const int hi = lane >> 4;

  f32x4 acc[4][4];
#pragma unroll
  for (int m = 0; m < 4; ++m)
#pragma unroll
    for (int n = 0; n < 4; ++n) acc[m][n] = (f32x4){0.f, 0.f, 0.f, 0.f};

  // per-wave fragment base: A row-blocks bm*8 + wr*4 + m, B: bn*8 + wc*4 + n
  const unsigned char* Ab = Xq + (((size_t)(bm * 8 + wr * 4)) << 10) + lane * 16;
  const unsigned char* Bb = Yq + (((size_t)(bn * 8 + wc * 4)) << 10) + lane * 16;

#define LOADF(da, db, g) do {                                                  \
    const unsigned char* pa_ = Ab + ((size_t)(g) << 19);                       \
    const unsigned char* pb_ = Bb + ((size_t)(g) << 19);                       \
    da[0] = *(const i32x4*)(pa_);                                              \
    da[1] = *(const i32x4*)(pa_ + 1024);                                       \
    da[2] = *(const i32x4*)(pa_ + 2048);                                       \
    da[3] = *(const i32x4*)(pa_ + 3072);                                       \
    db[0] = *(const i32x4*)(pb_);                                              \
    db[1] = *(const i32x4*)(pb_ + 1024);                                       \
    db[2] = *(const i32x4*)(pb_ + 2048);                                       \
    db[3] = *(const i32x4*)(pb_ + 3072);                                       \
  } while (0)

#define MM(aa, bb) do {                                                        \
    _Pragma("unroll")                                                          \
    for (int m_ = 0; m_ < 4; ++m_) {                                           \
      i32x8 av_ = {aa[m_][0], aa[m_][1], aa[m_][2], aa[m_][3], 0, 0, 0, 0};    \
      _Pragma("unroll")                                                        \
      for (int n_ = 0; n_ < 4; ++n_) {                                         \
        i32x8 bv_ = {bb[n_][0], bb[n_][1], bb[n_][2], bb[n_][3], 0, 0, 0, 0};  \
        acc[m_][n_] = __builtin_amdgcn_mfma_scale_f32_16x16x128_f8f6f4(        \
            av_, bv_, acc[m_][n_], 4, 4, 0, SCALE_I32, 0, SCALE_I32);          \
      }                                                                        \
    }                                                                          \
  } while (0)

  // depth-3 register pipeline: 3 rotating fragment sets, loads 2 groups ahead
  i32x4 Af[3][4], Bf[3][4];
  LOADF(Af[0], Bf[0], 0);
  LOADF(Af[1], Bf[1], 1);
#pragma unroll
  for (int g = 0; g < NKG; ++g) {
    if (g + 2 < NKG) LOADF(Af[(g + 2) % 3], Bf[(g + 2) % 3], g + 2);
    MM(Af[g % 3], Bf[g % 3]);
  }
#undef LOADF
#undef MM

  // ---- epilogue: exp + per-tile row/col sums ----
  // D layout (16x16 shapes): row = m*16 + hi*4 + q, col = n*16 + lo
  float rp[4][4];
  float cp[4];
#pragma unroll
  for (int m = 0; m < 4; ++m)
#pragma unroll
    for (int q = 0; q < 4; ++q) rp[m][q] = 0.f;
#pragma unroll
  for (int n = 0; n < 4; ++n) cp[n] = 0.f;

#pragma unroll
  for (int m = 0; m < 4; ++m)
#pragma unroll
    for (int n = 0; n < 4; ++n)
#pragma unroll
      for (int q = 0; q < 4; ++q) {
        float e = __expf(acc[m][n][q]);
        rp[m][q] += e;
        cp[n] += e;
      }

#pragma unroll
  for (int m = 0; m < 4; ++m)
#pragma unroll
    for (int q = 0; q < 4; ++q) {
      float v = rp[m][q];
      v += __shfl_xor(v, 1);
      v += __shfl_xor(v, 2);
      v += __shfl_xor(v, 4);
      v += __shfl_xor(v, 8);
      rp[m][q] = v;
    }
#pragma unroll
  for (int n = 0; n < 4; ++n) {
    float v = cp[n];
    v += __shfl_xor(v, 16);
    v += __shfl_xor(v, 32);
    cp[n] = v;
  }

  if (lo == 0) {
#pragma unroll
    for (int m = 0; m < 4; ++m)
#pragma unroll
      for (int q = 0; q < 4; ++q)
        rsum2[wc][wr * 64 + m * 16 + hi * 4 + q] = rp[m][q];
  }
  if (hi == 0) {
#pragma unroll
    for (int n = 0; n < 4; ++n)
      csum2[wr][wc * 64 + n * 16 + lo] = cp[n];
  }
  __syncthreads();

  if (tid < 128) {
    rowpart[(size_t)bn * BSZ + tileRow + tid] = rsum2[0][tid] + rsum2[1][tid];
    colpart[(size_t)bm * BSZ + tileCol + tid] = csum2[0][tid] + csum2[1][tid];
  }
}

// ---------- kernel 3: reduce partials + final expression ----------
__global__ void __launch_bounds__(256) k_final(const float* __restrict__ rowpart,
                                               const float* __restrict__ colpart,
                                               const float* __restrict__ dg,
                                               float* __restrict__ out) {
  const int k = blockIdx.x * 256 + threadIdx.x;
  float rs = 0.f, cs = 0.f;
#pragma unroll 8
  for (int s = 0; s < NTILE; ++s) {
    rs += rowpart[(size_t)s * BSZ + k];
    cs += colpart[(size_t)s * BSZ + k];
  }
  float d = dg[k];
  float p = __expf(d);
  out[k] = logf(cs - p) + logf(rs - p) - 2.0f * d;
}

extern "C" void kernel_launch(void* const* d_in, const int* in_sizes, int n_in,
                              void* d_out, int out_size, void* d_ws, size_t ws_size,
                              hipStream_t stream) {
  const float* X = (const float*)d_in[0];
  const float* Y = (const float*)d_in[1];
  float* out = (float*)d_out;

  char* ws = (char*)d_ws;
  // layout: Xq (8MB) | Yq (8MB) | diag (32KB) | rowpart (2MB) | colpart (2MB)
  unsigned char* Xq = (unsigned char*)ws;
  unsigned char* Yq = (unsigned char*)(ws + (size_t)BSZ * DIM / 2);
  float* diag = (float*)(ws + (size_t)BSZ * DIM);
  float* rowpart = (float*)(ws + (size_t)BSZ * DIM + BSZ * 4);
  float* colpart = (float*)(ws + (size_t)BSZ * DIM + BSZ * 4 + (size_t)NTILE * BSZ * 4);

  k_prep<<<BSZ, 256, 0, stream>>>(X, Y, Xq, Yq, diag);
  k_gemm<<<NTILE * NTILE, 256, 0, stream>>>(Xq, Yq, rowpart, colpart);
  k_final<<<BSZ / 256, 256, 0, stream>>>(rowpart, colpart, diag, out);
}